// Round 1
// baseline (212.642 us; speedup 1.0000x reference)
//
#include <hip/hip_runtime.h>
#include <math.h>

#define N_NODES    50000
#define N_G_EDGES  400000
#define N_LG_EDGES 600000
#define N_HEADS    4
#define OUT_FEATS  64
#define EPSV       0.001f
#define PI_F       3.14159265358979323846f

// ---------------- Kernel A: pack per-g-edge atomic numbers + node degree ----
__global__ void pack_keys_kernel(const int* __restrict__ an,
                                 const int* __restrict__ gsrc,
                                 const int* __restrict__ gdst,
                                 int* __restrict__ kk,
                                 float* __restrict__ cnt_g) {
    int g = blockIdx.x * blockDim.x + threadIdx.x;
    if (g >= N_G_EDGES) return;
    int s = gsrc[g];
    int ks = an[s];
    int kd = an[gdst[g]];
    kk[g] = ks | (kd << 8);
    atomicAdd(&cnt_g[s], 1.0f);
}

// ---------------- Kernel B1: lg-edge counts per g-edge ---------------------
__global__ void lg_count_kernel(const int* __restrict__ lgsrc,
                                float* __restrict__ cnt_lg) {
    int e = blockIdx.x * blockDim.x + threadIdx.x;
    if (e >= N_LG_EDGES) return;
    atomicAdd(&cnt_lg[lgsrc[e]], 1.0f);
}

// ---------------- Kernel B2: per lg-edge spatial -> node stats -------------
__global__ void lg_accum_kernel(const int* __restrict__ lgsrc,
                                const int* __restrict__ lgdst,
                                const float* __restrict__ costheta,
                                const float* __restrict__ dnr,
                                const float* __restrict__ pa,
                                const float* __restrict__ pb,
                                const float* __restrict__ pc,
                                const float* __restrict__ pd,
                                const int* __restrict__ kk,
                                const int* __restrict__ gsrc,
                                const float* __restrict__ cnt_lg,
                                float* __restrict__ Tsum) {
    int e = blockIdx.x * blockDim.x + threadIdx.x;
    if (e >= N_LG_EDGES) return;

    int ls = lgsrc[e];
    int ld = lgdst[e];
    int kks = kk[ls];
    int kkd = kk[ld];
    int ka = kks & 0xff;
    int kb = kks >> 8;
    int kc = kkd >> 8;
    int per = (ka == kc) ? 1 : 0;
    int cen = (kb == ka && kb == kc) ? 1 : 0;
    int key = per * 2 + cen;

    float ct = fminf(fmaxf(costheta[e], -EPSV), EPSV);
    float theta = acosf(ct);
    float dn = dnr[e];
    float dn2 = dn * dn;

    int node = gsrc[ls];
    float inv = 1.0f / fmaxf(cnt_lg[ls], 1.0f);
    float* base = Tsum + ((size_t)node * 16 + key * 4);

#pragma unroll
    for (int h = 0; h < N_HEADS; ++h) {
        float B = fmodf(pb[h], PI_F);
        float ang = powf((cosf(pa[h] * theta + B) + 1.0f) * 0.5f, pc[h]);
        float rad = expf(-pd[h] * dn2);
        float sp = rad * ang * inv;
        atomicAdd(base + h, sp);
    }
}

// ---------------- Kernel D: per (node, feat) output ------------------------
__global__ void node_out_kernel(const float* __restrict__ Tsum,
                                const float* __restrict__ cnt_g,
                                const float* __restrict__ VT,
                                float* __restrict__ out) {
    int j = blockIdx.x * blockDim.x + threadIdx.x; // n*64 + f
    if (j >= N_NODES * OUT_FEATS) return;
    int n = j >> 6;
    int f = j & 63;
    float inv = 1.0f / fmaxf(cnt_g[n], 1.0f);
    const float* T = Tsum + (size_t)n * 16;
    float acc = 0.0f;
#pragma unroll
    for (int k = 0; k < 4; ++k) {
#pragma unroll
        for (int h = 0; h < 4; ++h) {
            acc += VT[k * (OUT_FEATS * N_HEADS) + f * 4 + h] * T[k * 4 + h];
        }
    }
    out[j] = acc * inv;
}

extern "C" void kernel_launch(void* const* d_in, const int* in_sizes, int n_in,
                              void* d_out, int out_size, void* d_ws, size_t ws_size,
                              hipStream_t stream) {
    const int*   an       = (const int*)d_in[0];
    const int*   gsrc     = (const int*)d_in[1];
    const int*   gdst     = (const int*)d_in[2];
    const int*   lgsrc    = (const int*)d_in[3];
    const int*   lgdst    = (const int*)d_in[4];
    const float* costheta = (const float*)d_in[5];
    const float* dnr      = (const float*)d_in[6];
    const float* pa       = (const float*)d_in[7];
    const float* pb       = (const float*)d_in[8];
    const float* pc       = (const float*)d_in[9];
    const float* pd       = (const float*)d_in[10];
    const float* vt       = (const float*)d_in[11];
    float* out = (float*)d_out;

    char* ws = (char*)d_ws;
    // layout (bytes): kk[400000 int]        @ 0         (1,600,000)
    //                 cnt_lg[400000 f32]    @ 1,600,000 (1,600,000)
    //                 Tsum[50000*16 f32]    @ 3,200,000 (3,200,000)
    //                 cnt_g[50000 f32]      @ 6,400,000 (  200,000)
    int*   kk     = (int*)(ws + 0);
    float* cnt_lg = (float*)(ws + 1600000);
    float* Tsum   = (float*)(ws + 3200000);
    float* cnt_g  = (float*)(ws + 6400000);

    // zero the accumulator region (cnt_lg .. cnt_g): 5,000,000 bytes
    hipMemsetAsync(ws + 1600000, 0, 5000000, stream);

    dim3 blk(256);
    pack_keys_kernel<<<dim3((N_G_EDGES + 255) / 256), blk, 0, stream>>>(
        an, gsrc, gdst, kk, cnt_g);
    lg_count_kernel<<<dim3((N_LG_EDGES + 255) / 256), blk, 0, stream>>>(
        lgsrc, cnt_lg);
    lg_accum_kernel<<<dim3((N_LG_EDGES + 255) / 256), blk, 0, stream>>>(
        lgsrc, lgdst, costheta, dnr, pa, pb, pc, pd, kk, gsrc, cnt_lg, Tsum);
    node_out_kernel<<<dim3((N_NODES * OUT_FEATS + 255) / 256), blk, 0, stream>>>(
        Tsum, cnt_g, vt, out);
}

// Round 2
// 107.223 us; speedup vs baseline: 1.9832x; 1.9832x over previous
//
#include <hip/hip_runtime.h>
#include <math.h>

typedef unsigned long long u64;
typedef unsigned int u32;

#define N_NODES    50000
#define N_G_EDGES  400000
#define N_LG_EDGES 600000
#define OUT_FEATS  64
#define EPSV       0.001f
#define PI_F       3.14159265358979323846f
#define FXSCALE    512.0f
#define INV_FXSCALE (1.0f/512.0f)

// ws layout (bytes):
//   kk8    u8 [400000]          @ 0         ( 400,000)
//   R      u64[400000]          @ 400,000   (3,200,000)
//   cnt_lg u16 as u32[200000]   @ 3,600,000 (  800,000)
//   Tsum   u64[50000*4]         @ 4,400,000 (1,600,000)
//   cnt_g  u16 as u32[25000]    @ 6,000,000 (  100,000)
// total 6,100,000 bytes; zero range [3,600,000 .. 6,100,000)

// K1: pack per-g-edge atomic numbers; count g-edges per node and lg-edges per g-edge.
__global__ void k1_pack_count(const int* __restrict__ an,
                              const int* __restrict__ gsrc,
                              const int* __restrict__ gdst,
                              const int* __restrict__ lgsrc,
                              unsigned char* __restrict__ kk8,
                              u32* __restrict__ cnt_lg,
                              u32* __restrict__ cnt_g) {
    int i = blockIdx.x * blockDim.x + threadIdx.x;
    if (i < N_G_EDGES) {
        int s = gsrc[i];
        kk8[i] = (unsigned char)(an[s] | (an[gdst[i]] << 4));
        atomicAdd(&cnt_g[s >> 1], 1u << (16 * (s & 1)));
    }
    if (i < N_LG_EDGES) {
        int g = lgsrc[i];
        atomicAdd(&cnt_lg[g >> 1], 1u << (16 * (g & 1)));
    }
}

// K2: per-g-edge record {inv_cnt_lg f32 | gsrc 16b | kk 8b} -> one 8B gather in K3
__global__ void k2_build_r(const int* __restrict__ gsrc,
                           const unsigned char* __restrict__ kk8,
                           const u32* __restrict__ cnt_lg,
                           u64* __restrict__ R) {
    int g = blockIdx.x * blockDim.x + threadIdx.x;
    if (g >= N_G_EDGES) return;
    u32 w = cnt_lg[g >> 1];
    u32 c = (w >> (16 * (g & 1))) & 0xffffu;
    float inv = 1.0f / (float)(c < 1u ? 1u : c);
    R[g] = ((u64)__float_as_uint(inv) << 32)
         | ((u64)(u32)gsrc[g] << 8)
         | (u64)kk8[g];
}

// K3: main per-lg-edge kernel. ONE u64 atomic per edge (4 heads as 16b fixed-point).
__global__ void k3_accum(const int* __restrict__ lgsrc,
                         const int* __restrict__ lgdst,
                         const float* __restrict__ costheta,
                         const float* __restrict__ dnr,
                         const float* __restrict__ pa,
                         const float* __restrict__ pb,
                         const float* __restrict__ pc,
                         const float* __restrict__ pd,
                         const unsigned char* __restrict__ kk8,
                         const u64* __restrict__ R,
                         u64* __restrict__ Tsum) {
    int e = blockIdx.x * blockDim.x + threadIdx.x;
    if (e >= N_LG_EDGES) return;

    int ls = lgsrc[e];
    int ld = lgdst[e];
    u64 r = R[ls];
    int ka = (int)(r & 0xf);
    int kb = (int)((r >> 4) & 0xf);
    int node = (int)((r >> 8) & 0xffff);
    float inv = __uint_as_float((u32)(r >> 32));
    int kd = kk8[ld] >> 4;

    int key = ((ka == kd) ? 2 : 0) + ((kb == ka && kb == kd) ? 1 : 0);

    float ct = fminf(fmaxf(costheta[e], -EPSV), EPSV);
    float theta = acosf(ct);
    float dn = dnr[e];
    float dn2 = dn * dn;

    u64 q = 0;
#pragma unroll
    for (int h = 0; h < 4; ++h) {
        float B = fmodf(pb[h], PI_F);
        float ang = __powf((__cosf(pa[h] * theta + B) + 1.0f) * 0.5f, pc[h]);
        float rad = __expf(-pd[h] * dn2);
        float sp = rad * ang * inv;                    // in [0,1]
        q |= (u64)(u32)(sp * FXSCALE + 0.5f) << (16 * h);
    }
    atomicAdd(&Tsum[(size_t)node * 4 + key], q);
}

// K4: per (node, feat) output: 4x4 (key,head) FMA against value table.
__global__ void k4_out(const u64* __restrict__ Tsum,
                       const u32* __restrict__ cnt_g,
                       const float* __restrict__ VT,
                       float* __restrict__ out) {
    int j = blockIdx.x * blockDim.x + threadIdx.x;
    if (j >= N_NODES * OUT_FEATS) return;
    int n = j >> 6;
    int f = j & 63;
    u32 cg = (cnt_g[n >> 1] >> (16 * (n & 1))) & 0xffffu;
    float invg = 1.0f / (float)(cg < 1u ? 1u : cg);
    const u64* T = Tsum + (size_t)n * 4;
    float acc = 0.0f;
#pragma unroll
    for (int k = 0; k < 4; ++k) {
        u64 t = T[k];
#pragma unroll
        for (int h = 0; h < 4; ++h) {
            float tv = (float)((u32)(t >> (16 * h)) & 0xffffu);
            acc += VT[k * (OUT_FEATS * 4) + f * 4 + h] * tv;
        }
    }
    out[j] = acc * INV_FXSCALE * invg;
}

extern "C" void kernel_launch(void* const* d_in, const int* in_sizes, int n_in,
                              void* d_out, int out_size, void* d_ws, size_t ws_size,
                              hipStream_t stream) {
    const int*   an       = (const int*)d_in[0];
    const int*   gsrc     = (const int*)d_in[1];
    const int*   gdst     = (const int*)d_in[2];
    const int*   lgsrc    = (const int*)d_in[3];
    const int*   lgdst    = (const int*)d_in[4];
    const float* costheta = (const float*)d_in[5];
    const float* dnr      = (const float*)d_in[6];
    const float* pa       = (const float*)d_in[7];
    const float* pb       = (const float*)d_in[8];
    const float* pc       = (const float*)d_in[9];
    const float* pd       = (const float*)d_in[10];
    const float* vt       = (const float*)d_in[11];
    float* out = (float*)d_out;

    char* ws = (char*)d_ws;
    unsigned char* kk8    = (unsigned char*)(ws + 0);
    u64*           R      = (u64*)(ws + 400000);
    u32*           cnt_lg = (u32*)(ws + 3600000);
    u64*           Tsum   = (u64*)(ws + 4400000);
    u32*           cnt_g  = (u32*)(ws + 6000000);

    hipMemsetAsync(ws + 3600000, 0, 2500000, stream);

    dim3 blk(256);
    k1_pack_count<<<dim3((N_LG_EDGES + 255) / 256), blk, 0, stream>>>(
        an, gsrc, gdst, lgsrc, kk8, cnt_lg, cnt_g);
    k2_build_r<<<dim3((N_G_EDGES + 255) / 256), blk, 0, stream>>>(
        gsrc, kk8, cnt_lg, R);
    k3_accum<<<dim3((N_LG_EDGES + 255) / 256), blk, 0, stream>>>(
        lgsrc, lgdst, costheta, dnr, pa, pb, pc, pd, kk8, R, Tsum);
    k4_out<<<dim3((N_NODES * OUT_FEATS + 255) / 256), blk, 0, stream>>>(
        Tsum, cnt_g, vt, out);
}